// Round 3
// baseline (276.339 us; speedup 1.0000x reference)
//
#include <hip/hip_runtime.h>
#include <math.h>

static constexpr int BROWS   = 16384;
static constexpr int NC      = 784;
static constexpr int TR      = 4;      // rows/block: 4*784*4B = 12544 B LDS
static constexpr int THREADS = 256;
static constexpr int NREP    = 4;      // replicated stat accumulators
static constexpr float EPS   = 1e-5f;
static constexpr float INV_B = 1.0f / (float)BROWS;

#if defined(__has_builtin)
#if __has_builtin(__builtin_amdgcn_global_load_lds)
#define HAVE_ASYNC_LDS 1
#endif
#endif

__device__ __forceinline__ void stage16(const float4* g, float4* l) {
#ifdef HAVE_ASYNC_LDS
    __builtin_amdgcn_global_load_lds(
        (const __attribute__((address_space(1))) void*)g,
        (__attribute__((address_space(3))) void*)l, 16, 0, 0);
#else
    *l = *g;
#endif
}

__device__ __forceinline__ float gelu_exact(float x) {
    return 0.5f * x * (1.0f + erff(x * 0.7071067811865475f));
}

// ---------------- Fused L1 -> gelu -> L2 -> gelu (+ stats for bn2a) ----------------
// h1 never touches HBM: computed into registers, written back over the x LDS buffer.
__global__ __launch_bounds__(THREADS, 7)
void layer12(const float* __restrict__ x,
             const int*   __restrict__ idx1, const float* __restrict__ W1, const float* __restrict__ b1,
             const int*   __restrict__ idx2, const float* __restrict__ W2, const float* __restrict__ b2,
             float* __restrict__ u2, float* __restrict__ ssum, float* __restrict__ ssq)
{
    __shared__ float rows[TR * NC];
    const int    tid  = threadIdx.x;
    const size_t row0 = (size_t)blockIdx.x * TR;

    {   // async-stage TR rows of x
        const float4* in4 = (const float4*)(x + row0 * NC);
        float4*       r4  = (float4*)rows;
        for (int i = tid; i < TR * NC / 4; i += THREADS) stage16(in4 + i, r4 + i);
    }
    __syncthreads();

    // L1 into registers
    float h[4][TR];
    #pragma unroll
    for (int g = 0; g < 4; ++g) {
        const int j = tid + g * THREADS;
        if (j < NC) {
            const int   i0 = idx1[2 * j], i1 = idx1[2 * j + 1];
            const float w0 = W1[2 * j],  w1 = W1[2 * j + 1], bb = b1[j];
            #pragma unroll
            for (int r = 0; r < TR; ++r) {
                const float acc = fmaf(rows[r * NC + i0], w0, fmaf(rows[r * NC + i1], w1, bb));
                h[g][r] = gelu_exact(acc);
            }
        }
    }
    __syncthreads();           // all reads of x done
    #pragma unroll
    for (int g = 0; g < 4; ++g) {
        const int j = tid + g * THREADS;
        if (j < NC)
            #pragma unroll
            for (int r = 0; r < TR; ++r) rows[r * NC + j] = h[g][r];
    }
    __syncthreads();           // h1 resident in LDS

    // L2 (K=4) + gelu + stats
    for (int j = tid; j < NC; j += THREADS) {
        int ji[4]; float jw[4];
        #pragma unroll
        for (int k = 0; k < 4; ++k) { ji[k] = idx2[4 * j + k]; jw[k] = W2[4 * j + k]; }
        const float jb = b2[j];
        float s1 = 0.0f, s2 = 0.0f;
        #pragma unroll
        for (int r = 0; r < TR; ++r) {
            float acc = jb;
            #pragma unroll
            for (int k = 0; k < 4; ++k) acc = fmaf(rows[r * NC + ji[k]], jw[k], acc);
            const float u = gelu_exact(acc);
            u2[(row0 + r) * NC + j] = u;
            s1 += u; s2 = fmaf(u, u, s2);
        }
        const int rep = blockIdx.x & (NREP - 1);
        atomicAdd(&ssum[rep * NC + j], s1);
        atomicAdd(&ssq[rep * NC + j],  s2);
    }
}

// ------------- Generic layer: bn(prev stats) folded into weights, sparse, act -------------
// out[b,j] = act( sum_k (in[b,c_k]*sc[c_k]+sh[c_k]) * W[j,k] + b[j] )
//          = act( sum_k in[b,c_k]*(W[j,k]*sc[c_k]) + (b[j] + sum_k W[j,k]*sh[c_k]) )
// sc/sh computed per block from the raw atomic sums (hot in L2).
template<int K, bool STATS, bool RELU>
__global__ __launch_bounds__(THREADS, K == 8 ? 6 : 8)
void sparse_bn_layer(const float* __restrict__ in,
                     const int*   __restrict__ idx, const float* __restrict__ W,
                     const float* __restrict__ bias,
                     const float* __restrict__ gamma, const float* __restrict__ beta,
                     const float* __restrict__ psum,  const float* __restrict__ psq,
                     float* __restrict__ out, float* __restrict__ ssum, float* __restrict__ ssq)
{
    __shared__ float rows[TR * NC];
    __shared__ float s_sc[NC], s_sh[NC];
    const int    tid  = threadIdx.x;
    const size_t row0 = (size_t)blockIdx.x * TR;

    {   // issue the row DMA first; fold math below overlaps with it
        const float4* in4 = (const float4*)(in + row0 * NC);
        float4*       r4  = (float4*)rows;
        for (int i = tid; i < TR * NC / 4; i += THREADS) stage16(in4 + i, r4 + i);
    }
    // finalize BN of the previous layer into scale/shift (per block, L2-served)
    for (int j = tid; j < NC; j += THREADS) {
        float s1 = 0.0f, s2 = 0.0f;
        #pragma unroll
        for (int r = 0; r < NREP; ++r) { s1 += psum[r * NC + j]; s2 += psq[r * NC + j]; }
        const float m   = s1 * INV_B;
        const float var = fmaf(-m, m, s2 * INV_B);
        const float sc  = gamma[j] * rsqrtf(var + EPS);
        s_sc[j] = sc;
        s_sh[j] = fmaf(-m, sc, beta[j]);
    }
    __syncthreads();   // covers DMA drain + sc/sh writes

    for (int j = tid; j < NC; j += THREADS) {
        int ji[K]; float jw[K];
        float jb = bias[j];
        #pragma unroll
        for (int k = 0; k < K; ++k) {
            const int   c = idx[K * j + k];
            const float w = W[K * j + k];
            ji[k] = c;
            jw[k] = w * s_sc[c];
            jb    = fmaf(w, s_sh[c], jb);
        }
        float s1 = 0.0f, s2 = 0.0f;
        #pragma unroll
        for (int r = 0; r < TR; ++r) {
            float acc = jb;
            #pragma unroll
            for (int k = 0; k < K; ++k) acc = fmaf(rows[r * NC + ji[k]], jw[k], acc);
            const float u = RELU ? fmaxf(acc, 0.0f) : gelu_exact(acc);
            out[(row0 + r) * NC + j] = u;
            if (STATS) { s1 += u; s2 = fmaf(u, u, s2); }
        }
        if (STATS) {
            const int rep = blockIdx.x & (NREP - 1);
            atomicAdd(&ssum[rep * NC + j], s1);
            atomicAdd(&ssq[rep * NC + j],  s2);
        }
    }
}

extern "C" void kernel_launch(void* const* d_in, const int* in_sizes, int n_in,
                              void* d_out, int out_size, void* d_ws, size_t ws_size,
                              hipStream_t stream)
{
    const float* x    = (const float*)d_in[0];
    const int*   idx1 = (const int*)  d_in[1];
    const float* W1   = (const float*)d_in[2];
    const float* b1   = (const float*)d_in[3];
    const int*   idx2 = (const int*)  d_in[4];
    const float* W2   = (const float*)d_in[5];
    const float* b2   = (const float*)d_in[6];
    const int*   idx3 = (const int*)  d_in[7];
    const float* W3   = (const float*)d_in[8];
    const float* b3   = (const float*)d_in[9];
    const float* g2   = (const float*)d_in[10];
    const float* be2  = (const float*)d_in[11];
    const float* g3   = (const float*)d_in[12];
    const float* be3  = (const float*)d_in[13];
    float* out = (float*)d_out;

    const size_t BN_ELEMS = (size_t)BROWS * NC;
    // Buffer plan (no alias within any kernel):
    //   K_A: r x      -> w ws0 (u2)
    //   K_B: r ws0    -> w out (u3)
    //   K_C: r out    -> w ws0 (u4; u2 dead)
    //   K_D: r ws0    -> w out
    float* ws0 = (float*)d_ws;
    float* p   = ws0 + BN_ELEMS;
    float* sum2a = p; p += NREP * NC;  float* ssq2a = p; p += NREP * NC;
    float* sum3  = p; p += NREP * NC;  float* ssq3  = p; p += NREP * NC;
    float* sum2b = p; p += NREP * NC;  float* ssq2b = p; p += NREP * NC;

    hipMemsetAsync(sum2a, 0, 6 * NREP * NC * sizeof(float), stream);

    const dim3 grid(BROWS / TR), blk(THREADS);

    // L1+L2 fused: u2 = gelu(sp2(gelu(sp1(x)))), bn2a stats
    layer12<<<grid, blk, 0, stream>>>(x, idx1, W1, b1, idx2, W2, b2, ws0, sum2a, ssq2a);
    // L3: u3 = gelu(sp3(bn2a(u2))), bn3 stats
    sparse_bn_layer<8, true, false><<<grid, blk, 0, stream>>>(
        ws0, idx3, W3, b3, g2, be2, sum2a, ssq2a, out, sum3, ssq3);
    // L4: u4 = gelu(sp2(bn3(u3))), bn2b stats
    sparse_bn_layer<4, true, false><<<grid, blk, 0, stream>>>(
        out, idx2, W2, b2, g3, be3, sum3, ssq3, ws0, sum2b, ssq2b);
    // L5: out = relu(sp1(bn2b(u4)))
    sparse_bn_layer<2, false, true><<<grid, blk, 0, stream>>>(
        ws0, idx1, W1, b1, g2, be2, sum2b, ssq2b, out, nullptr, nullptr);
}

// Round 4
// 205.839 us; speedup vs baseline: 1.3425x; 1.3425x over previous
//
#include <hip/hip_runtime.h>
#include <math.h>

static constexpr int BROWS   = 16384;
static constexpr int NC      = 784;
static constexpr int TR      = 16;     // rows/block (bf16 rows = 25088 B LDS)
static constexpr int THREADS = 512;
static constexpr int NREP    = 4;      // replicated stat accumulators
static constexpr float EPS   = 1e-5f;
static constexpr float INV_B = 1.0f / (float)BROWS;

#if defined(__has_builtin)
#if __has_builtin(__builtin_amdgcn_global_load_lds)
#define HAVE_ASYNC_LDS 1
#endif
#if __has_builtin(__builtin_amdgcn_rcpf)
#define HAVE_RCPF 1
#endif
#endif

__device__ __forceinline__ void stage16(const float4* g, float4* l) {
#ifdef HAVE_ASYNC_LDS
    __builtin_amdgcn_global_load_lds(
        (const __attribute__((address_space(1))) void*)g,
        (__attribute__((address_space(3))) void*)l, 16, 0, 0);
#else
    *l = *g;
#endif
}

// ---- bf16 helpers (raw u16 storage; RNE convert) ----
__device__ __forceinline__ float b2f(unsigned short h) {
    union { unsigned u; float f; } v; v.u = ((unsigned)h) << 16; return v.f;
}
__device__ __forceinline__ unsigned short f2b(float f) {
    union { float f; unsigned u; } v; v.f = f;
    const unsigned r = v.u + 0x7fffu + ((v.u >> 16) & 1u);
    return (unsigned short)(r >> 16);
}
__device__ __forceinline__ unsigned pack2(float lo, float hi) {
    return (unsigned)f2b(lo) | ((unsigned)f2b(hi) << 16);
}

__device__ __forceinline__ float fast_rcp(float x) {
#ifdef HAVE_RCPF
    return __builtin_amdgcn_rcpf(x);
#else
    return 1.0f / x;
#endif
}

// Exact-accuracy gelu via Abramowitz-Stegun 7.1.26 erf (|eps| <= 1.5e-7), branchless.
__device__ __forceinline__ float gelu_f(float x) {
    const float a = fabsf(x) * 0.7071067811865475f;      // |x|/sqrt(2)
    const float t = fast_rcp(fmaf(0.3275911f, a, 1.0f));
    float p = fmaf(t, 1.061405429f, -1.453152027f);
    p = fmaf(t, p, 1.421413741f);
    p = fmaf(t, p, -0.284496736f);
    p = fmaf(t, p, 0.254829592f);
    p *= t;
    const float e  = __expf(-a * a);
    const float er = fmaf(-p, e, 1.0f);                  // erf(|x|/sqrt2)
    return 0.5f * x * (1.0f + copysignf(er, x));
}

// ---------------- K_A: fused L1 -> gelu -> L2 -> gelu (+ bn2a stats) ----------------
// x staged to LDS as bf16; h1 computed in-place per 8-row subtile (gather is row-local);
// u2 written to global as bf16.
__global__ __launch_bounds__(THREADS, 6)
void layer12(const float* __restrict__ x,
             const int* __restrict__ idx1, const float* __restrict__ W1, const float* __restrict__ b1,
             const int* __restrict__ idx2, const float* __restrict__ W2, const float* __restrict__ b2,
             unsigned short* __restrict__ u2, float* __restrict__ ssum, float* __restrict__ ssq)
{
    __shared__ __align__(16) unsigned short rows[TR * NC];   // 25088 B
    const int tid  = threadIdx.x;
    const int row0 = blockIdx.x * TR;

    {   // stage + convert x -> bf16 rows (coalesced float4 reads)
        const float4* x4 = (const float4*)(x + (size_t)row0 * NC);
        uint2* r2 = (uint2*)rows;
        for (int i = tid; i < TR * NC / 4; i += THREADS) {
            const float4 v = x4[i];
            uint2 pk; pk.x = pack2(v.x, v.y); pk.y = pack2(v.z, v.w);
            r2[i] = pk;
        }
    }
    __syncthreads();

    // L1 in-place per 8-row subtile (row-local gather => only same-row hazards)
    for (int s = 0; s < TR; s += 8) {
        float h[2][8];
        #pragma unroll
        for (int g = 0; g < 2; ++g) {
            const int j = tid + g * THREADS;
            if (j < NC) {
                const int   i0 = idx1[2 * j], i1 = idx1[2 * j + 1];
                const float w0 = W1[2 * j],   w1 = W1[2 * j + 1], bb = b1[j];
                #pragma unroll
                for (int r = 0; r < 8; ++r) {
                    const float acc = fmaf(b2f(rows[(s + r) * NC + i0]), w0,
                                      fmaf(b2f(rows[(s + r) * NC + i1]), w1, bb));
                    h[g][r] = gelu_f(acc);
                }
            }
        }
        __syncthreads();
        #pragma unroll
        for (int g = 0; g < 2; ++g) {
            const int j = tid + g * THREADS;
            if (j < NC)
                #pragma unroll
                for (int r = 0; r < 8; ++r) rows[(s + r) * NC + j] = f2b(h[g][r]);
        }
        __syncthreads();
    }

    // L2 (K=4) + gelu + stats
    #pragma unroll
    for (int g = 0; g < 2; ++g) {
        const int j = tid + g * THREADS;
        if (j < NC) {
            int ji[4]; float jw[4];
            #pragma unroll
            for (int k = 0; k < 4; ++k) { ji[k] = idx2[4 * j + k]; jw[k] = W2[4 * j + k]; }
            const float jb = b2[j];
            float s1 = 0.0f, s2 = 0.0f;
            #pragma unroll 4
            for (int r = 0; r < TR; ++r) {
                float acc = jb;
                #pragma unroll
                for (int k = 0; k < 4; ++k) acc = fmaf(b2f(rows[r * NC + ji[k]]), jw[k], acc);
                const float u = gelu_f(acc);
                u2[(size_t)(row0 + r) * NC + j] = f2b(u);
                s1 += u; s2 = fmaf(u, u, s2);
            }
            const int rep = blockIdx.x & (NREP - 1);
            atomicAdd(&ssum[rep * NC + j], s1);
            atomicAdd(&ssq[rep * NC + j],  s2);
        }
    }
}

// -------- K_B/C/D: bn(prev stats) folded into weights -> sparse -> act (+ stats) --------
// FINAL: relu + fp32 output + no stats; else gelu + bf16 output + stats.
template<int K, bool FINAL>
__global__ __launch_bounds__(THREADS, 6)
void layer_bn(const unsigned short* __restrict__ in,
              const int* __restrict__ idx, const float* __restrict__ W, const float* __restrict__ bias,
              const float* __restrict__ gamma, const float* __restrict__ beta,
              const float* __restrict__ psum,  const float* __restrict__ psq,
              void* __restrict__ outv, float* __restrict__ ssum, float* __restrict__ ssq)
{
    __shared__ __align__(16) unsigned short rows[TR * NC];   // 25088 B
    __shared__ float s_sc[NC], s_sh[NC];                     // 6272 B
    const int tid  = threadIdx.x;
    const int row0 = blockIdx.x * TR;

    {   // async DMA stage of TR bf16 rows (overlaps the fold math below)
        const float4* src = (const float4*)(in + (size_t)row0 * NC);
        float4*       dst = (float4*)rows;
        for (int i = tid; i < TR * NC * 2 / 16; i += THREADS) stage16(src + i, dst + i);
    }
    // finalize previous BN into scale/shift (reads are L2-hot; overlaps DMA)
    for (int j = tid; j < NC; j += THREADS) {
        float s1 = 0.0f, s2 = 0.0f;
        #pragma unroll
        for (int r = 0; r < NREP; ++r) { s1 += psum[r * NC + j]; s2 += psq[r * NC + j]; }
        const float m   = s1 * INV_B;
        const float var = fmaf(-m, m, s2 * INV_B);
        const float sc  = gamma[j] * rsqrtf(var + EPS);
        s_sc[j] = sc;
        s_sh[j] = fmaf(-m, sc, beta[j]);
    }
    __syncthreads();   // drains DMA + publishes sc/sh

    #pragma unroll
    for (int g = 0; g < 2; ++g) {
        const int j = tid + g * THREADS;
        if (j < NC) {
            int ji[K]; float jw[K];
            float jb = bias[j];
            #pragma unroll
            for (int k = 0; k < K; ++k) {
                const int   c = idx[K * j + k];
                const float w = W[K * j + k];
                ji[k] = c;
                jw[k] = w * s_sc[c];
                jb    = fmaf(w, s_sh[c], jb);
            }
            float s1 = 0.0f, s2 = 0.0f;
            #pragma unroll 4
            for (int r = 0; r < TR; ++r) {
                float acc = jb;
                #pragma unroll
                for (int k = 0; k < K; ++k) acc = fmaf(b2f(rows[r * NC + ji[k]]), jw[k], acc);
                if (FINAL) {
                    ((float*)outv)[(size_t)(row0 + r) * NC + j] = fmaxf(acc, 0.0f);
                } else {
                    const float u = gelu_f(acc);
                    ((unsigned short*)outv)[(size_t)(row0 + r) * NC + j] = f2b(u);
                    s1 += u; s2 = fmaf(u, u, s2);
                }
            }
            if (!FINAL) {
                const int rep = blockIdx.x & (NREP - 1);
                atomicAdd(&ssum[rep * NC + j], s1);
                atomicAdd(&ssq[rep * NC + j],  s2);
            }
        }
    }
}

extern "C" void kernel_launch(void* const* d_in, const int* in_sizes, int n_in,
                              void* d_out, int out_size, void* d_ws, size_t ws_size,
                              hipStream_t stream)
{
    const float* x    = (const float*)d_in[0];
    const int*   idx1 = (const int*)  d_in[1];
    const float* W1   = (const float*)d_in[2];
    const float* b1   = (const float*)d_in[3];
    const int*   idx2 = (const int*)  d_in[4];
    const float* W2   = (const float*)d_in[5];
    const float* b2   = (const float*)d_in[6];
    const int*   idx3 = (const int*)  d_in[7];
    const float* W3   = (const float*)d_in[8];
    const float* b3   = (const float*)d_in[9];
    const float* g2   = (const float*)d_in[10];
    const float* be2  = (const float*)d_in[11];
    const float* g3   = (const float*)d_in[12];
    const float* be3  = (const float*)d_in[13];
    float* out = (float*)d_out;

    const size_t BN_ELEMS = (size_t)BROWS * NC;
    // bf16 ping-pong intermediates in the workspace:
    //   K_A: r x   -> w ws0 (u2)
    //   K_B: r ws0 -> w ws1 (u3)
    //   K_C: r ws1 -> w ws0 (u4; u2 dead)
    //   K_D: r ws0 -> w out (fp32)
    unsigned short* ws0 = (unsigned short*)d_ws;
    unsigned short* ws1 = ws0 + BN_ELEMS;
    float* p = (float*)(ws1 + BN_ELEMS);
    float* sum2a = p; p += NREP * NC;  float* ssq2a = p; p += NREP * NC;
    float* sum3  = p; p += NREP * NC;  float* ssq3  = p; p += NREP * NC;
    float* sum2b = p; p += NREP * NC;  float* ssq2b = p; p += NREP * NC;

    hipMemsetAsync(sum2a, 0, 6 * NREP * NC * sizeof(float), stream);

    const dim3 grid(BROWS / TR), blk(THREADS);

    layer12<<<grid, blk, 0, stream>>>(x, idx1, W1, b1, idx2, W2, b2, ws0, sum2a, ssq2a);
    layer_bn<8, false><<<grid, blk, 0, stream>>>(
        ws0, idx3, W3, b3, g2, be2, sum2a, ssq2a, ws1, sum3, ssq3);
    layer_bn<4, false><<<grid, blk, 0, stream>>>(
        ws1, idx2, W2, b2, g3, be3, sum3, ssq3, ws0, sum2b, ssq2b);
    layer_bn<2, true><<<grid, blk, 0, stream>>>(
        ws0, idx1, W1, b1, g2, be2, sum2b, ssq2b, out, nullptr, nullptr);
}

// Round 6
// 192.552 us; speedup vs baseline: 1.4351x; 1.0690x over previous
//
#include <hip/hip_runtime.h>
#include <math.h>

static constexpr int BROWS   = 16384;
static constexpr int NC      = 784;
static constexpr int TRB     = 16;              // rows per block
static constexpr int THREADS = 512;
static constexpr int NBLK    = BROWS / TRB;     // 1024 blocks
static constexpr int NSLOT   = 2;               // ceil(784/512) column slots per thread
static constexpr int NREP    = 4;               // replicated stat accumulators
static constexpr float EPS   = 1e-5f;
static constexpr float INV_B = 1.0f / (float)BROWS;

#if defined(__has_builtin)
#if __has_builtin(__builtin_amdgcn_global_load_lds)
#define HAVE_ASYNC_LDS 1
#endif
#if __has_builtin(__builtin_amdgcn_rcpf)
#define HAVE_RCPF 1
#endif
#endif

__device__ __forceinline__ void stage16(const float4* g, float4* l) {
#ifdef HAVE_ASYNC_LDS
    __builtin_amdgcn_global_load_lds(
        (const __attribute__((address_space(1))) void*)g,
        (__attribute__((address_space(3))) void*)l, 16, 0, 0);
#else
    *l = *g;
#endif
}

// ---- bf16 helpers (raw u16 storage; RNE convert) ----
__device__ __forceinline__ unsigned short f2b(float f) {
    union { float f; unsigned u; } v; v.f = f;
    const unsigned r = v.u + 0x7fffu + ((v.u >> 16) & 1u);
    return (unsigned short)(r >> 16);
}
__device__ __forceinline__ unsigned pack2(float lo, float hi) {
    return (unsigned)f2b(lo) | ((unsigned)f2b(hi) << 16);
}
__device__ __forceinline__ unsigned long long pack4(float a, float b, float c, float d) {
    return (unsigned long long)pack2(a, b) | ((unsigned long long)pack2(c, d) << 32);
}
// u64 = 4 bf16 rows of one column: bits[15:0]=r0, [31:16]=r1, [47:32]=r2, [63:48]=r3
__device__ __forceinline__ void unpack4(unsigned long long v, float f[4]) {
    const unsigned lo = (unsigned)v, hi = (unsigned)(v >> 32);
    union { unsigned u; float f; } a, b, c, d;
    a.u = lo << 16; b.u = lo & 0xffff0000u; c.u = hi << 16; d.u = hi & 0xffff0000u;
    f[0] = a.f; f[1] = b.f; f[2] = c.f; f[3] = d.f;
}

__device__ __forceinline__ float fast_rcp(float x) {
#ifdef HAVE_RCPF
    return __builtin_amdgcn_rcpf(x);
#else
    return 1.0f / x;
#endif
}

// Exact-accuracy gelu via A&S 7.1.26 erf (|eps| <= 1.5e-7), branchless. (validated R4)
__device__ __forceinline__ float gelu_f(float x) {
    const float a = fabsf(x) * 0.7071067811865475f;
    const float t = fast_rcp(fmaf(0.3275911f, a, 1.0f));
    float p = fmaf(t, 1.061405429f, -1.453152027f);
    p = fmaf(t, p, 1.421413741f);
    p = fmaf(t, p, -0.284496736f);
    p = fmaf(t, p, 0.254829592f);
    p *= t;
    const float e  = __expf(-a * a);
    const float er = fmaf(-p, e, 1.0f);
    return 0.5f * x * (1.0f + copysignf(er, x));
}

// ---------------- K_A: fused L1 -> gelu -> L2 -> gelu (+ bn2a stats) ----------------
// x (fp32 row-major) staged into quad-interleaved bf16 LDS; L1 done in place per
// 8-row half; u2 stored to global in quad layout (contiguous 25 KB per block).
__global__ __launch_bounds__(THREADS, 8)
void layer12(const float* __restrict__ x,
             const int* __restrict__ idx1, const float* __restrict__ W1, const float* __restrict__ b1,
             const int* __restrict__ idx2, const float* __restrict__ W2, const float* __restrict__ b2,
             unsigned long long* __restrict__ uq2,
             float* __restrict__ ssum, float* __restrict__ ssq)
{
    __shared__ unsigned long long quad[4 * NC];   // 25088 B
    const int tid  = threadIdx.x;
    const int row0 = blockIdx.x * TRB;

    // stage: per-row coalesced dword loads, pack 4 rows -> one ds_write_b64
    #pragma unroll
    for (int slot = 0; slot < NSLOT; ++slot) {
        const int c = tid + slot * THREADS;
        if (c < NC) {
            #pragma unroll
            for (int q = 0; q < 4; ++q) {
                const size_t base = (size_t)(row0 + 4 * q) * NC + c;
                quad[q * NC + c] = pack4(x[base], x[base + NC], x[base + 2 * NC], x[base + 3 * NC]);
            }
        }
    }
    __syncthreads();

    // L1 in place, two 8-row halves (gather is row-local; only same-row hazards)
    for (int half = 0; half < 2; ++half) {
        float h[NSLOT][8];
        #pragma unroll
        for (int slot = 0; slot < NSLOT; ++slot) {
            const int j = tid + slot * THREADS;
            if (j < NC) {
                const int   i0 = idx1[2 * j], i1 = idx1[2 * j + 1];
                const float w0 = W1[2 * j],   w1 = W1[2 * j + 1], bb = b1[j];
                #pragma unroll
                for (int qq = 0; qq < 2; ++qq) {
                    float f0[4], f1[4];
                    unpack4(quad[(2 * half + qq) * NC + i0], f0);
                    unpack4(quad[(2 * half + qq) * NC + i1], f1);
                    #pragma unroll
                    for (int rr = 0; rr < 4; ++rr)
                        h[slot][4 * qq + rr] = gelu_f(fmaf(f0[rr], w0, fmaf(f1[rr], w1, bb)));
                }
            }
        }
        __syncthreads();
        #pragma unroll
        for (int slot = 0; slot < NSLOT; ++slot) {
            const int j = tid + slot * THREADS;
            if (j < NC) {
                quad[(2 * half + 0) * NC + j] = pack4(h[slot][0], h[slot][1], h[slot][2], h[slot][3]);
                quad[(2 * half + 1) * NC + j] = pack4(h[slot][4], h[slot][5], h[slot][6], h[slot][7]);
            }
        }
        __syncthreads();
    }

    // L2 (K=4) + gelu + stats + quad store
    for (int slot = 0; slot < NSLOT; ++slot) {
        const int j = tid + slot * THREADS;
        if (j < NC) {
            int ji[4]; float jw[4];
            #pragma unroll
            for (int k = 0; k < 4; ++k) { ji[k] = idx2[4 * j + k]; jw[k] = W2[4 * j + k]; }
            const float jb = b2[j];
            float s1 = 0.0f, s2 = 0.0f;
            #pragma unroll
            for (int q = 0; q < 4; ++q) {
                float acc[4] = { jb, jb, jb, jb };
                #pragma unroll
                for (int k = 0; k < 4; ++k) {
                    float f[4];
                    unpack4(quad[q * NC + ji[k]], f);
                    #pragma unroll
                    for (int rr = 0; rr < 4; ++rr) acc[rr] = fmaf(f[rr], jw[k], acc[rr]);
                }
                float u[4];
                #pragma unroll
                for (int rr = 0; rr < 4; ++rr) {
                    u[rr] = gelu_f(acc[rr]);
                    s1 += u[rr]; s2 = fmaf(u[rr], u[rr], s2);
                }
                uq2[(size_t)(blockIdx.x * 4 + q) * NC + j] = pack4(u[0], u[1], u[2], u[3]);
            }
            const int rep = blockIdx.x & (NREP - 1);
            atomicAdd(&ssum[rep * NC + j], s1);
            atomicAdd(&ssq[rep * NC + j],  s2);
        }
    }
}

// -------- K_B/C/D: fold prev BN into weights -> sparse -> act (+ stats) --------
// Input tile is a contiguous 25088 B quad region: staged via global_load_lds x16.
// FINAL: relu + fp32 row-major output, no stats; else gelu + quad bf16 + stats.
template<int K, bool FINAL>
__global__ __launch_bounds__(THREADS, 8)
void layer_bn(const unsigned long long* __restrict__ uqin,
              const int* __restrict__ idx, const float* __restrict__ W, const float* __restrict__ bias,
              const float* __restrict__ gamma, const float* __restrict__ beta,
              const float* __restrict__ psum, const float* __restrict__ psq,
              unsigned long long* __restrict__ uqout, float* __restrict__ fout,
              float* __restrict__ ssum, float* __restrict__ ssq)
{
    __shared__ unsigned long long quad[4 * NC];   // 25088 B
    __shared__ float s_sc[NC], s_sh[NC];          //  6272 B
    const int tid  = threadIdx.x;
    const int row0 = blockIdx.x * TRB;

    {   // async DMA of the block's contiguous quad region (lane-linear dst: m104-safe)
        const float4* src = (const float4*)(uqin + (size_t)blockIdx.x * 4 * NC);
        float4*       dst = (float4*)quad;
        for (int i = tid; i < 4 * NC / 2; i += THREADS) stage16(src + i, dst + i);
    }
    // finalize previous BN into scale/shift (L2-hot reads; overlaps DMA)
    for (int j = tid; j < NC; j += THREADS) {
        float s1 = 0.0f, s2 = 0.0f;
        #pragma unroll
        for (int r = 0; r < NREP; ++r) { s1 += psum[r * NC + j]; s2 += psq[r * NC + j]; }
        const float m   = s1 * INV_B;
        const float var = fmaf(-m, m, s2 * INV_B);
        const float sc  = gamma[j] * rsqrtf(var + EPS);
        s_sc[j] = sc;
        s_sh[j] = fmaf(-m, sc, beta[j]);
    }
    __syncthreads();   // drains DMA + publishes sc/sh

    for (int slot = 0; slot < NSLOT; ++slot) {
        const int j = tid + slot * THREADS;
        if (j < NC) {
            int ji[K]; float jw[K];
            float jb = bias[j];
            #pragma unroll
            for (int k = 0; k < K; ++k) {
                const int   c = idx[K * j + k];
                const float w = W[K * j + k];
                ji[k] = c; jw[k] = w * s_sc[c]; jb = fmaf(w, s_sh[c], jb);
            }
            float s1 = 0.0f, s2 = 0.0f;
            #pragma unroll
            for (int q = 0; q < 4; ++q) {
                float acc[4] = { jb, jb, jb, jb };
                #pragma unroll
                for (int k = 0; k < K; ++k) {
                    float f[4];
                    unpack4(quad[q * NC + ji[k]], f);
                    #pragma unroll
                    for (int rr = 0; rr < 4; ++rr) acc[rr] = fmaf(f[rr], jw[k], acc[rr]);
                }
                if (FINAL) {
                    #pragma unroll
                    for (int rr = 0; rr < 4; ++rr)
                        fout[(size_t)(row0 + 4 * q + rr) * NC + j] = fmaxf(acc[rr], 0.0f);
                } else {
                    float u[4];
                    #pragma unroll
                    for (int rr = 0; rr < 4; ++rr) {
                        u[rr] = gelu_f(acc[rr]);
                        s1 += u[rr]; s2 = fmaf(u[rr], u[rr], s2);
                    }
                    uqout[(size_t)(blockIdx.x * 4 + q) * NC + j] = pack4(u[0], u[1], u[2], u[3]);
                }
            }
            if (!FINAL) {
                const int rep = blockIdx.x & (NREP - 1);
                atomicAdd(&ssum[rep * NC + j], s1);
                atomicAdd(&ssq[rep * NC + j],  s2);
            }
        }
    }
}

extern "C" void kernel_launch(void* const* d_in, const int* in_sizes, int n_in,
                              void* d_out, int out_size, void* d_ws, size_t ws_size,
                              hipStream_t stream)
{
    const float* x    = (const float*)d_in[0];
    const int*   idx1 = (const int*)  d_in[1];
    const float* W1   = (const float*)d_in[2];
    const float* b1   = (const float*)d_in[3];
    const int*   idx2 = (const int*)  d_in[4];
    const float* W2   = (const float*)d_in[5];
    const float* b2   = (const float*)d_in[6];
    const int*   idx3 = (const int*)  d_in[7];
    const float* W3   = (const float*)d_in[8];
    const float* b3   = (const float*)d_in[9];
    const float* g2   = (const float*)d_in[10];
    const float* be2  = (const float*)d_in[11];
    const float* g3   = (const float*)d_in[12];
    const float* be3  = (const float*)d_in[13];
    float* out = (float*)d_out;

    const size_t QN = (size_t)NBLK * 4 * NC;      // u64 elements per intermediate
    // Quad-layout bf16 ping-pong:
    //   K_A: r x   -> w ws0 (u2)
    //   K_B: r ws0 -> w ws1 (u3)
    //   K_C: r ws1 -> w ws0 (u4; u2 dead)
    //   K_D: r ws0 -> w out (fp32 row-major)
    unsigned long long* ws0 = (unsigned long long*)d_ws;
    unsigned long long* ws1 = ws0 + QN;
    float* p = (float*)(ws1 + QN);
    float* sum2a = p; p += NREP * NC;  float* ssq2a = p; p += NREP * NC;
    float* sum3  = p; p += NREP * NC;  float* ssq3  = p; p += NREP * NC;
    float* sum2b = p; p += NREP * NC;  float* ssq2b = p; p += NREP * NC;

    hipMemsetAsync(sum2a, 0, 6 * NREP * NC * sizeof(float), stream);

    const dim3 grid(NBLK), blk(THREADS);

    layer12<<<grid, blk, 0, stream>>>(x, idx1, W1, b1, idx2, W2, b2, ws0, sum2a, ssq2a);
    layer_bn<8, false><<<grid, blk, 0, stream>>>(
        ws0, idx3, W3, b3, g2, be2, sum2a, ssq2a, ws1, nullptr, sum3, ssq3);
    layer_bn<4, false><<<grid, blk, 0, stream>>>(
        ws1, idx2, W2, b2, g3, be3, sum3, ssq3, ws0, nullptr, sum2b, ssq2b);
    layer_bn<2, true><<<grid, blk, 0, stream>>>(
        ws0, idx1, W1, b1, g2, be2, sum2b, ssq2b, nullptr, out, nullptr, nullptr);
}